// Round 7
// baseline (7734.333 us; speedup 1.0000x reference)
//
#include <hip/hip_runtime.h>

#define Bn   128
#define Tn   512
#define Kn   12
#define Hn   256
#define NWG  256
#define ARR      32768            // 128*256 elements per state array
#define SSTRIDE  (4*ARR)          // ushorts per state buffer (h_hi,h_lo,c_hi,c_lo)

typedef __attribute__((ext_vector_type(8))) short bf16x8;
typedef __attribute__((ext_vector_type(4))) float f32x4;

__device__ inline unsigned short f2bf(float x) {
  union { float f; unsigned u; } v; v.f = x;
  unsigned r = v.u + 0x7fffu + ((v.u >> 16) & 1u);
  return (unsigned short)(r >> 16);
}
__device__ inline float bf2f(unsigned short h) {
  union { unsigned u; float f; } v; v.u = ((unsigned)h) << 16;
  return v.f;
}
__device__ inline float sigmf(float x) { return 1.0f / (1.0f + __expf(-x)); }

// Volatile 16B load: LLVM lowers volatile global loads on gfx94x/gfx950 with
// sc0 sc1 (bypass vL1+L2, serve at MALL, no allocate) -> state reads are
// always coherence-point fresh WITHOUT any per-step buffer_inv.
__device__ inline bf16x8 vload16(const unsigned short* p) {
  return *(const volatile bf16x8*)p;
}

// ROUND-6 PROVEN KERNEL (absmax 0.0, 6.96ms) with ONE change: state A-loads
// are volatile (MALL-fresh) and the per-step acquire fence is DELETED ->
// zero cache-maintenance ops per step. Soundness: owner stores are sc1
// write-through atomics, drained (vmcnt(0)) by __syncthreads before the
// arrival RMW, so flag==gen implies all step-t state is visible at MALL;
// volatile loads issued after poll success read MALL directly. Side win:
// with no inv, xd/dt lines persist in L2 across steps (staging was an HBM
// miss every step before).
__global__ void __launch_bounds__(256, 1) mtlstm_kernel(
    const float* __restrict__ xd, const float* __restrict__ dtp,
    const float* __restrict__ wih, const float* __restrict__ whh,
    const float* __restrict__ bias, const float* __restrict__ wdc,
    const float* __restrict__ bdc, unsigned char* __restrict__ ws)
{
  __shared__ __align__(16) float xs_lds[32 * Kn];
  __shared__ __align__(16) float dt_lds[32 * Kn];
  __shared__ float g_lds[32 * 16];      // activated gates [b_local][jj*4+g]
  __shared__ float dsum_lds[32 * 48];   // decomp contribs [b_local][jj][k]

  unsigned* cnt = (unsigned*)ws;
  unsigned* flg = cnt + 1;
  unsigned short* state = (unsigned short*)(ws + 128);
  float* h_final = (float*)(ws + 128 + 2 * SSTRIDE * 2);

  const int tid = threadIdx.x;
  const int wv  = tid >> 6;        // wave 0: gates(h); waves 1..3: decomp(c)
  const int l   = tid & 63;
  const int n   = l & 15;          // MFMA col / A-row within tile
  const int oct = l >> 4;          // k-octet

  const int wgid = blockIdx.x;
  const int bg = wgid >> 6;        // batch group 0..3 (32 b each)
  const int j0 = (wgid & 63) * 4;  // 4 j-columns per WG

  // ---- one-time weight setup: per-lane 16 cols x 256 k, split hi/lo bf16 ----
  const float* rowp;
  float biasv;
  int kd = 0, jjd = 0;
  float wx[12];
  if (wv == 0) {
    int jj = n >> 2, g = n & 3;
    int grow = g * Hn + j0 + jj;
    rowp = whh + (size_t)grow * Hn;
    biasv = bias[grow];
#pragma unroll
    for (int kk = 0; kk < 12; ++kk) wx[kk] = wih[grow * 12 + kk];
  } else {
    int q = (wv - 1) * 16 + n;     // 0..47
    int jj = q / 12;
    int k  = q - jj * 12;
    kd = k; jjd = jj;
    rowp = wdc + ((size_t)k * Hn + (j0 + jj)) * Hn;
    biasv = bdc[k * Hn + j0 + jj];
#pragma unroll
    for (int kk = 0; kk < 12; ++kk) wx[kk] = 0.f;
  }

  bf16x8 wh[8], wl[8];
#pragma unroll
  for (int ks = 0; ks < 8; ++ks) {
    const float* p = rowp + ks * 32 + oct * 8;
#pragma unroll
    for (int e = 0; e < 8; ++e) {
      float x = p[e];
      unsigned short hi = f2bf(x);
      unsigned short lo = f2bf(x - bf2f(hi));
      wh[ks][e] = (short)hi;
      wl[ks][e] = (short)lo;
    }
  }

  const int aoff0 = (bg * 32 + n) * Hn + oct * 8;  // M-tile 0 A offset
  const int aoff1 = aoff0 + 16 * Hn;               // M-tile 1
  const int hsel  = (wv == 0) ? 0 : 2 * ARR;       // h arrays vs c arrays

  float c_reg[4] = {0.f, 0.f, 0.f, 0.f};  // exact fp32 c, owners tid<32 (4 j each)
  unsigned gen = 0;

  for (int t = 0; t < Tn; ++t) {
    const unsigned short* sb = state + (t & 1) * SSTRIDE + hsel;

    // stage x_t, dt_t for this WG's 32 b's (read-only inputs: plain cached loads,
    // now L2-resident across steps since nothing invalidates L2 anymore)
    if (tid < 96) {
      int bl = tid / 3, ch = tid % 3;
      float4 v = *(const float4*)(xd + ((size_t)(bg * 32 + bl) * Tn + t) * Kn + ch * 4);
      *(float4*)(&xs_lds[bl * 12 + ch * 4]) = v;
    } else if (tid < 192) {
      int q2 = tid - 96;
      int bl = q2 / 3, ch = q2 % 3;
      float4 v = *(const float4*)(dtp + ((size_t)(bg * 32 + bl) * Tn + t) * Kn + ch * 4);
      *(float4*)(&dt_lds[bl * 12 + ch * 4]) = v;
    }

    // ---- GEMM: 2 M-tiles x 1 N-tile, K=256, split-bf16 (3 MFMA) ----
    //      A-fragments via VOLATILE loads (MALL-fresh, no inv needed)
    f32x4 acc0 = {0.f, 0.f, 0.f, 0.f};
    f32x4 acc1 = {0.f, 0.f, 0.f, 0.f};
#pragma unroll
    for (int ks = 0; ks < 8; ++ks) {
      int o = ks * 32;
      bf16x8 a0h = vload16(sb + aoff0 + o);
      bf16x8 a1h = vload16(sb + aoff1 + o);
      bf16x8 a0l = vload16(sb + ARR + aoff0 + o);
      bf16x8 a1l = vload16(sb + ARR + aoff1 + o);
      acc0 = __builtin_amdgcn_mfma_f32_16x16x32_bf16(a0h, wh[ks], acc0, 0, 0, 0);
      acc1 = __builtin_amdgcn_mfma_f32_16x16x32_bf16(a1h, wh[ks], acc1, 0, 0, 0);
      acc0 = __builtin_amdgcn_mfma_f32_16x16x32_bf16(a0h, wl[ks], acc0, 0, 0, 0);
      acc1 = __builtin_amdgcn_mfma_f32_16x16x32_bf16(a1h, wl[ks], acc1, 0, 0, 0);
      acc0 = __builtin_amdgcn_mfma_f32_16x16x32_bf16(a0l, wh[ks], acc0, 0, 0, 0);
      acc1 = __builtin_amdgcn_mfma_f32_16x16x32_bf16(a1l, wh[ks], acc1, 0, 0, 0);
    }

    __syncthreads();   // x/dt staged; LDS phase boundary

    // ---- epilogue: D layout row=(oct*4+r) (=b_local within tile), col=n ----
    if (wv == 0) {
      int g = n & 3;
#pragma unroll
      for (int mt = 0; mt < 2; ++mt) {
        f32x4 a = mt ? acc1 : acc0;
#pragma unroll
        for (int r = 0; r < 4; ++r) {
          int bl = mt * 16 + oct * 4 + r;
          float xwv = 0.f;
#pragma unroll
          for (int kk = 0; kk < 12; ++kk) xwv += xs_lds[bl * 12 + kk] * wx[kk];
          float v = a[r] + biasv + xwv;
          float act = (g == 2) ? tanhf(v) : sigmf(v);
          g_lds[bl * 16 + n] = act;
        }
      }
    } else {
#pragma unroll
      for (int mt = 0; mt < 2; ++mt) {
        f32x4 a = mt ? acc1 : acc0;
#pragma unroll
        for (int r = 0; r < 4; ++r) {
          int bl = mt * 16 + oct * 4 + r;
          float v = a[r] + biasv;
          float cs = tanhf(v);
          float dtv = dt_lds[bl * 12 + kd];
          float coef = 1.0f / __logf(2.718281828459045f + dtv) - 1.0f;
          dsum_lds[bl * 48 + jjd * 12 + kd] = cs * coef;
        }
      }
    }
    __syncthreads();

    // ---- state update: tid<32, one batch row each, packed 8B sc1 stores ----
    if (tid < 32) {
      int b = tid;
      union P { unsigned short u[4]; unsigned long long q; } ph, pl, pc, pq;
#pragma unroll
      for (int jj = 0; jj < 4; ++jj) {
        float iv = g_lds[b * 16 + jj * 4 + 0];
        float fv = g_lds[b * 16 + jj * 4 + 1];
        float gv = g_lds[b * 16 + jj * 4 + 2];
        float ov = g_lds[b * 16 + jj * 4 + 3];
        float S = 0.f;
#pragma unroll
        for (int k = 0; k < 12; ++k) S += dsum_lds[b * 48 + jj * 12 + k];
        float cst = c_reg[jj] + S;
        float cn = fv * cst + iv * gv;
        float hn = ov * tanhf(cn);
        c_reg[jj] = cn;
        ph.u[jj] = f2bf(hn);
        pl.u[jj] = f2bf(hn - bf2f(ph.u[jj]));
        pc.u[jj] = f2bf(cn);
        pq.u[jj] = f2bf(cn - bf2f(pc.u[jj]));
        if (t == Tn - 1)
          h_final[(size_t)(bg * 32 + b) * Hn + j0 + jj] = hn;
      }
      unsigned long long* db = (unsigned long long*)state
          + (size_t)((t + 1) & 1) * (SSTRIDE / 4)
          + (size_t)(bg * 32 + b) * 64 + (j0 >> 2);
      __hip_atomic_store(db + 0 * (ARR / 4), ph.q, __ATOMIC_RELAXED, __HIP_MEMORY_SCOPE_AGENT);
      __hip_atomic_store(db + 1 * (ARR / 4), pl.q, __ATOMIC_RELAXED, __HIP_MEMORY_SCOPE_AGENT);
      __hip_atomic_store(db + 2 * (ARR / 4), pc.q, __ATOMIC_RELAXED, __HIP_MEMORY_SCOPE_AGENT);
      __hip_atomic_store(db + 3 * (ARR / 4), pq.q, __ATOMIC_RELAXED, __HIP_MEMORY_SCOPE_AGENT);
    }

    // ---- grid barrier: ZERO cache-maintenance ops. Relaxed monotone
    //      arrival + publish + poll (round-6 proven forms), no fence. ----
    ++gen;
    __syncthreads();   // per-wave s_waitcnt vmcnt(0): all WG stores ack'd at MALL
    if (tid == 0) {
      unsigned old = __hip_atomic_fetch_add(cnt, 1u, __ATOMIC_RELAXED,
                                            __HIP_MEMORY_SCOPE_AGENT);
      if (old == gen * NWG - 1) {
        __hip_atomic_store(flg, gen, __ATOMIC_RELAXED, __HIP_MEMORY_SCOPE_AGENT);
      } else {
        while (__hip_atomic_load(flg, __ATOMIC_RELAXED,
                                 __HIP_MEMORY_SCOPE_AGENT) < gen)
          __builtin_amdgcn_s_sleep(2);
      }
    }
    __syncthreads();
  }
}

__global__ void out_gemv(const float* __restrict__ hf, const float* __restrict__ lw,
                         const float* __restrict__ lb, float* __restrict__ out)
{
  int b = blockIdx.x;
  int l = threadIdx.x;
  const float* row = hf + b * Hn;
  float s = row[l] * lw[l] + row[l + 64] * lw[l + 64]
          + row[l + 128] * lw[l + 128] + row[l + 192] * lw[l + 192];
#pragma unroll
  for (int off = 32; off > 0; off >>= 1) s += __shfl_down(s, off, 64);
  if (l == 0) out[b] = s + lb[0];
}

extern "C" void kernel_launch(void* const* d_in, const int* in_sizes, int n_in,
                              void* d_out, int out_size, void* d_ws, size_t ws_size,
                              hipStream_t stream)
{
  const float* xd   = (const float*)d_in[0];
  const float* dtp  = (const float*)d_in[1];
  const float* wih  = (const float*)d_in[2];
  const float* whh  = (const float*)d_in[3];
  const float* bias = (const float*)d_in[4];
  const float* wdc  = (const float*)d_in[5];
  const float* bdc  = (const float*)d_in[6];
  const float* lw   = (const float*)d_in[7];
  const float* lb   = (const float*)d_in[8];
  float* out = (float*)d_out;
  unsigned char* ws = (unsigned char*)d_ws;

  // zero barrier + both state buffers (ws is poisoned 0xAA each call)
  hipMemsetAsync(ws, 0, 128 + 2 * SSTRIDE * 2, stream);

  void* args[] = { (void*)&xd, (void*)&dtp, (void*)&wih, (void*)&whh,
                   (void*)&bias, (void*)&wdc, (void*)&bdc, (void*)&ws };
  hipLaunchCooperativeKernel((const void*)mtlstm_kernel, dim3(NWG), dim3(256),
                             args, 0, stream);

  const float* hf = (const float*)(ws + 128 + 2 * SSTRIDE * 2);
  out_gemv<<<dim3(Bn), dim3(64), 0, stream>>>(hf, lw, lb, out);
}

// Round 8
// 5044.410 us; speedup vs baseline: 1.5332x; 1.5332x over previous
//
#include <hip/hip_runtime.h>

#define Bn   128
#define Tn   512
#define Kn   12
#define Hn   256
#define NWG  256
#define ARR      32768            // 128*256 elements per state array
#define SSTRIDE  (4*ARR)          // ushorts per state buffer (h_hi,h_lo,c_hi,c_lo)
#define SLOTS_BYTES 1024          // 4 groups x 64 slots x 4B (256B/group, line-separated)

typedef __attribute__((ext_vector_type(8))) short bf16x8;
typedef __attribute__((ext_vector_type(4))) float f32x4;

__device__ inline unsigned short f2bf(float x) {
  union { float f; unsigned u; } v; v.f = x;
  unsigned r = v.u + 0x7fffu + ((v.u >> 16) & 1u);
  return (unsigned short)(r >> 16);
}
__device__ inline float bf2f(unsigned short h) {
  union { unsigned u; float f; } v; v.u = ((unsigned)h) << 16;
  return v.f;
}
__device__ inline float sigmf(float x) { return 1.0f / (1.0f + __expf(-x)); }

// ROUND-6 PROVEN DATA PATH (absmax 0.0, 6.96ms) with the BARRIER replaced:
//  (a) the 4 batch-groups are fully independent recurrences (each WG reads и
//      writes only state rows bg*32..bg*32+31) -> four 64-WG group barriers
//      instead of one 256-WG grid barrier;
//  (b) arrival is a slot-per-WG relaxed store (zero same-address RMWs — the
//      256 serialized fetch_adds were ~12us/step, the round-6 floor), and
//      every WG's wave 0 polls all 64 slots itself (lane l watches slot l,
//      __all ballot) — no publisher hop, no flag.
// Ordering: __syncthreads drains vmcnt per wave, so each WG's sc1
// write-through state stores are at the coherence point BEFORE its slot
// store issues; slot==gen therefore implies that WG's state is visible.
// Keep round-6's single acquire fence (tid0; CU-wide vL1 + XCD-L2 inv) so
// the next step's plain cached state loads can't hit stale lines.
__global__ void __launch_bounds__(256, 1) mtlstm_kernel(
    const float* __restrict__ xd, const float* __restrict__ dtp,
    const float* __restrict__ wih, const float* __restrict__ whh,
    const float* __restrict__ bias, const float* __restrict__ wdc,
    const float* __restrict__ bdc, unsigned char* __restrict__ ws)
{
  __shared__ __align__(16) float xs_lds[32 * Kn];
  __shared__ __align__(16) float dt_lds[32 * Kn];
  __shared__ float g_lds[32 * 16];      // activated gates [b_local][jj*4+g]
  __shared__ float dsum_lds[32 * 48];   // decomp contribs [b_local][jj][k]

  unsigned* slots = (unsigned*)ws;                       // [4][64], monotone gens
  unsigned short* state = (unsigned short*)(ws + SLOTS_BYTES);
  float* h_final = (float*)(ws + SLOTS_BYTES + 2 * SSTRIDE * 2);

  const int tid = threadIdx.x;
  const int wv  = tid >> 6;        // wave 0: gates(h); waves 1..3: decomp(c)
  const int l   = tid & 63;
  const int n   = l & 15;          // MFMA col / A-row within tile
  const int oct = l >> 4;          // k-octet

  const int wgid = blockIdx.x;
  const int bg = wgid >> 6;        // batch group 0..3 (32 b each)
  const int j0 = (wgid & 63) * 4;  // 4 j-columns per WG
  unsigned* gslot = slots + bg * 64;   // this group's 64 slots (2 cache lines)

  // ---- one-time weight setup: per-lane 16 cols x 256 k, split hi/lo bf16 ----
  const float* rowp;
  float biasv;
  int kd = 0, jjd = 0;
  float wx[12];
  if (wv == 0) {
    int jj = n >> 2, g = n & 3;
    int grow = g * Hn + j0 + jj;
    rowp = whh + (size_t)grow * Hn;
    biasv = bias[grow];
#pragma unroll
    for (int kk = 0; kk < 12; ++kk) wx[kk] = wih[grow * 12 + kk];
  } else {
    int q = (wv - 1) * 16 + n;     // 0..47
    int jj = q / 12;
    int k  = q - jj * 12;
    kd = k; jjd = jj;
    rowp = wdc + ((size_t)k * Hn + (j0 + jj)) * Hn;
    biasv = bdc[k * Hn + j0 + jj];
#pragma unroll
    for (int kk = 0; kk < 12; ++kk) wx[kk] = 0.f;
  }

  bf16x8 wh[8], wl[8];
#pragma unroll
  for (int ks = 0; ks < 8; ++ks) {
    const float* p = rowp + ks * 32 + oct * 8;
#pragma unroll
    for (int e = 0; e < 8; ++e) {
      float x = p[e];
      unsigned short hi = f2bf(x);
      unsigned short lo = f2bf(x - bf2f(hi));
      wh[ks][e] = (short)hi;
      wl[ks][e] = (short)lo;
    }
  }

  const int aoff0 = (bg * 32 + n) * Hn + oct * 8;  // M-tile 0 A offset
  const int aoff1 = aoff0 + 16 * Hn;               // M-tile 1
  const int hsel  = (wv == 0) ? 0 : 2 * ARR;       // h arrays vs c arrays

  float c_reg[4] = {0.f, 0.f, 0.f, 0.f};  // exact fp32 c, owners tid<32 (4 j each)
  unsigned gen = 0;

  for (int t = 0; t < Tn; ++t) {
    const unsigned short* sb = state + (t & 1) * SSTRIDE + hsel;

    // stage x_t, dt_t for this WG's 32 b's (read-only inputs, plain cached)
    if (tid < 96) {
      int bl = tid / 3, ch = tid % 3;
      float4 v = *(const float4*)(xd + ((size_t)(bg * 32 + bl) * Tn + t) * Kn + ch * 4);
      *(float4*)(&xs_lds[bl * 12 + ch * 4]) = v;
    } else if (tid < 192) {
      int q2 = tid - 96;
      int bl = q2 / 3, ch = q2 % 3;
      float4 v = *(const float4*)(dtp + ((size_t)(bg * 32 + bl) * Tn + t) * Kn + ch * 4);
      *(float4*)(&dt_lds[bl * 12 + ch * 4]) = v;
    }

    // ---- GEMM: 2 M-tiles x 1 N-tile, K=256, split-bf16 (3 MFMA) ----
    f32x4 acc0 = {0.f, 0.f, 0.f, 0.f};
    f32x4 acc1 = {0.f, 0.f, 0.f, 0.f};
#pragma unroll
    for (int ks = 0; ks < 8; ++ks) {
      int o = ks * 32;
      bf16x8 a0h = *(const bf16x8*)(sb + aoff0 + o);
      bf16x8 a1h = *(const bf16x8*)(sb + aoff1 + o);
      bf16x8 a0l = *(const bf16x8*)(sb + ARR + aoff0 + o);
      bf16x8 a1l = *(const bf16x8*)(sb + ARR + aoff1 + o);
      acc0 = __builtin_amdgcn_mfma_f32_16x16x32_bf16(a0h, wh[ks], acc0, 0, 0, 0);
      acc1 = __builtin_amdgcn_mfma_f32_16x16x32_bf16(a1h, wh[ks], acc1, 0, 0, 0);
      acc0 = __builtin_amdgcn_mfma_f32_16x16x32_bf16(a0h, wl[ks], acc0, 0, 0, 0);
      acc1 = __builtin_amdgcn_mfma_f32_16x16x32_bf16(a1h, wl[ks], acc1, 0, 0, 0);
      acc0 = __builtin_amdgcn_mfma_f32_16x16x32_bf16(a0l, wh[ks], acc0, 0, 0, 0);
      acc1 = __builtin_amdgcn_mfma_f32_16x16x32_bf16(a1l, wh[ks], acc1, 0, 0, 0);
    }

    __syncthreads();   // x/dt staged; LDS phase boundary

    // ---- epilogue: D layout row=(oct*4+r) (=b_local within tile), col=n ----
    if (wv == 0) {
      int g = n & 3;
#pragma unroll
      for (int mt = 0; mt < 2; ++mt) {
        f32x4 a = mt ? acc1 : acc0;
#pragma unroll
        for (int r = 0; r < 4; ++r) {
          int bl = mt * 16 + oct * 4 + r;
          float xwv = 0.f;
#pragma unroll
          for (int kk = 0; kk < 12; ++kk) xwv += xs_lds[bl * 12 + kk] * wx[kk];
          float v = a[r] + biasv + xwv;
          float act = (g == 2) ? tanhf(v) : sigmf(v);
          g_lds[bl * 16 + n] = act;
        }
      }
    } else {
#pragma unroll
      for (int mt = 0; mt < 2; ++mt) {
        f32x4 a = mt ? acc1 : acc0;
#pragma unroll
        for (int r = 0; r < 4; ++r) {
          int bl = mt * 16 + oct * 4 + r;
          float v = a[r] + biasv;
          float cs = tanhf(v);
          float dtv = dt_lds[bl * 12 + kd];
          float coef = 1.0f / __logf(2.718281828459045f + dtv) - 1.0f;
          dsum_lds[bl * 48 + jjd * 12 + kd] = cs * coef;
        }
      }
    }
    __syncthreads();

    // ---- state update: tid<32, one batch row each, packed 8B sc1 stores ----
    if (tid < 32) {
      int b = tid;
      union P { unsigned short u[4]; unsigned long long q; } ph, pl, pc, pq;
#pragma unroll
      for (int jj = 0; jj < 4; ++jj) {
        float iv = g_lds[b * 16 + jj * 4 + 0];
        float fv = g_lds[b * 16 + jj * 4 + 1];
        float gv = g_lds[b * 16 + jj * 4 + 2];
        float ov = g_lds[b * 16 + jj * 4 + 3];
        float S = 0.f;
#pragma unroll
        for (int k = 0; k < 12; ++k) S += dsum_lds[b * 48 + jj * 12 + k];
        float cst = c_reg[jj] + S;
        float cn = fv * cst + iv * gv;
        float hn = ov * tanhf(cn);
        c_reg[jj] = cn;
        ph.u[jj] = f2bf(hn);
        pl.u[jj] = f2bf(hn - bf2f(ph.u[jj]));
        pc.u[jj] = f2bf(cn);
        pq.u[jj] = f2bf(cn - bf2f(pc.u[jj]));
        if (t == Tn - 1)
          h_final[(size_t)(bg * 32 + b) * Hn + j0 + jj] = hn;
      }
      unsigned long long* db = (unsigned long long*)state
          + (size_t)((t + 1) & 1) * (SSTRIDE / 4)
          + (size_t)(bg * 32 + b) * 64 + (j0 >> 2);
      __hip_atomic_store(db + 0 * (ARR / 4), ph.q, __ATOMIC_RELAXED, __HIP_MEMORY_SCOPE_AGENT);
      __hip_atomic_store(db + 1 * (ARR / 4), pl.q, __ATOMIC_RELAXED, __HIP_MEMORY_SCOPE_AGENT);
      __hip_atomic_store(db + 2 * (ARR / 4), pc.q, __ATOMIC_RELAXED, __HIP_MEMORY_SCOPE_AGENT);
      __hip_atomic_store(db + 3 * (ARR / 4), pq.q, __ATOMIC_RELAXED, __HIP_MEMORY_SCOPE_AGENT);
    }

    // ---- per-group (64-WG) barrier: slot store + distributed wave-0 poll.
    //      Zero same-address RMWs; one acquire inv per WG (round-6 proven). ----
    ++gen;
    __syncthreads();   // per-wave vmcnt(0): this WG's state stores ack'd at MALL
    if (tid == 0)
      __hip_atomic_store(gslot + (wgid & 63), gen, __ATOMIC_RELAXED,
                         __HIP_MEMORY_SCOPE_AGENT);
    if (wv == 0) {
      for (;;) {
        unsigned v = __hip_atomic_load(gslot + l, __ATOMIC_RELAXED,
                                       __HIP_MEMORY_SCOPE_AGENT);
        if (__all((int)(v >= gen))) break;
        __builtin_amdgcn_s_sleep(4);
      }
      if (tid == 0)
        __builtin_amdgcn_fence(__ATOMIC_ACQUIRE, "agent");  // inv vL1+L2, no wbl2
    }
    __syncthreads();
  }
}

__global__ void out_gemv(const float* __restrict__ hf, const float* __restrict__ lw,
                         const float* __restrict__ lb, float* __restrict__ out)
{
  int b = blockIdx.x;
  int l = threadIdx.x;
  const float* row = hf + b * Hn;
  float s = row[l] * lw[l] + row[l + 64] * lw[l + 64]
          + row[l + 128] * lw[l + 128] + row[l + 192] * lw[l + 192];
#pragma unroll
  for (int off = 32; off > 0; off >>= 1) s += __shfl_down(s, off, 64);
  if (l == 0) out[b] = s + lb[0];
}

extern "C" void kernel_launch(void* const* d_in, const int* in_sizes, int n_in,
                              void* d_out, int out_size, void* d_ws, size_t ws_size,
                              hipStream_t stream)
{
  const float* xd   = (const float*)d_in[0];
  const float* dtp  = (const float*)d_in[1];
  const float* wih  = (const float*)d_in[2];
  const float* whh  = (const float*)d_in[3];
  const float* bias = (const float*)d_in[4];
  const float* wdc  = (const float*)d_in[5];
  const float* bdc  = (const float*)d_in[6];
  const float* lw   = (const float*)d_in[7];
  const float* lb   = (const float*)d_in[8];
  float* out = (float*)d_out;
  unsigned char* ws = (unsigned char*)d_ws;

  // zero slots + both state buffers (ws is poisoned 0xAA each call)
  hipMemsetAsync(ws, 0, SLOTS_BYTES + 2 * SSTRIDE * 2, stream);

  void* args[] = { (void*)&xd, (void*)&dtp, (void*)&wih, (void*)&whh,
                   (void*)&bias, (void*)&wdc, (void*)&bdc, (void*)&ws };
  hipLaunchCooperativeKernel((const void*)mtlstm_kernel, dim3(NWG), dim3(256),
                             args, 0, stream);

  const float* hf = (const float*)(ws + SLOTS_BYTES + 2 * SSTRIDE * 2);
  out_gemv<<<dim3(Bn), dim3(64), 0, stream>>>(hf, lw, lb, out);
}

// Round 9
// 5039.273 us; speedup vs baseline: 1.5348x; 1.0010x over previous
//
#include <hip/hip_runtime.h>

#define Bn   128
#define Tn   512
#define Kn   12
#define Hn   256
#define NWG  256
#define ARR      32768            // 128*256 elements per state array
#define SSTRIDE  (4*ARR)          // ushorts per state buffer (h_hi,h_lo,c_hi,c_lo)
#define SLOTS_BYTES 1024          // 4 groups x 64 slots x 4B

typedef __attribute__((ext_vector_type(8))) short bf16x8;
typedef __attribute__((ext_vector_type(4))) float f32x4;

__device__ inline unsigned short f2bf(float x) {
  union { float f; unsigned u; } v; v.f = x;
  unsigned r = v.u + 0x7fffu + ((v.u >> 16) & 1u);
  return (unsigned short)(r >> 16);
}
__device__ inline float bf2f(unsigned short h) {
  union { unsigned u; float f; } v; v.u = ((unsigned)h) << 16;
  return v.f;
}
__device__ inline float sigmf(float x) { return 1.0f / (1.0f + __expf(-x)); }

// ROUND-8 PROVEN KERNEL (absmax 0.0, 5.04ms) with the barrier tail OVERLAPPED:
//  (a) only wave 0 writes state, so the arrival slot store needs only wave 0's
//      own s_waitcnt vmcnt(0) (inline asm) after the owner stores — the
//      all-wave pre-barrier __syncthreads is deleted and the slot store
//      issues ~0.5us earlier;
//  (b) waves 1-3 are idle during slot-store/poll/inv -> they stage the NEXT
//      step's x_t/dt_t into LDS during that window (state-independent work),
//      taking it off the critical path. One __syncthreads (D) joins.
// LDS hazard audit: xs/dt(t+1) writes are post-sync-C (wave0's xw read of
// xs(t) is in the epilogue, pre-C); owner's g/dsum(t) reads complete pre-D;
// next epilogue's g/dsum(t+1) writes are post-D. Coherence protocol
// (sc1 write-through stores, slot==gen ordering, per-WG acquire inv) is
// unchanged from round 8.
__global__ void __launch_bounds__(256, 1) mtlstm_kernel(
    const float* __restrict__ xd, const float* __restrict__ dtp,
    const float* __restrict__ wih, const float* __restrict__ whh,
    const float* __restrict__ bias, const float* __restrict__ wdc,
    const float* __restrict__ bdc, unsigned char* __restrict__ ws)
{
  __shared__ __align__(16) float xs_lds[32 * Kn];
  __shared__ __align__(16) float dt_lds[32 * Kn];
  __shared__ float g_lds[32 * 16];      // activated gates [b_local][jj*4+g]
  __shared__ float dsum_lds[32 * 48];   // decomp contribs [b_local][jj][k]

  unsigned* slots = (unsigned*)ws;                       // [4][64], monotone gens
  unsigned short* state = (unsigned short*)(ws + SLOTS_BYTES);
  float* h_final = (float*)(ws + SLOTS_BYTES + 2 * SSTRIDE * 2);

  const int tid = threadIdx.x;
  const int wv  = tid >> 6;        // wave 0: gates(h); waves 1..3: decomp(c)
  const int l   = tid & 63;
  const int n   = l & 15;          // MFMA col / A-row within tile
  const int oct = l >> 4;          // k-octet

  const int wgid = blockIdx.x;
  const int bg = wgid >> 6;        // batch group 0..3 (32 b each)
  const int j0 = (wgid & 63) * 4;  // 4 j-columns per WG
  unsigned* gslot = slots + bg * 64;

  // ---- one-time weight setup: per-lane 16 cols x 256 k, split hi/lo bf16 ----
  const float* rowp;
  float biasv;
  int kd = 0, jjd = 0;
  float wx[12];
  if (wv == 0) {
    int jj = n >> 2, g = n & 3;
    int grow = g * Hn + j0 + jj;
    rowp = whh + (size_t)grow * Hn;
    biasv = bias[grow];
#pragma unroll
    for (int kk = 0; kk < 12; ++kk) wx[kk] = wih[grow * 12 + kk];
  } else {
    int q = (wv - 1) * 16 + n;     // 0..47
    int jj = q / 12;
    int k  = q - jj * 12;
    kd = k; jjd = jj;
    rowp = wdc + ((size_t)k * Hn + (j0 + jj)) * Hn;
    biasv = bdc[k * Hn + j0 + jj];
#pragma unroll
    for (int kk = 0; kk < 12; ++kk) wx[kk] = 0.f;
  }

  bf16x8 wh[8], wl[8];
#pragma unroll
  for (int ks = 0; ks < 8; ++ks) {
    const float* p = rowp + ks * 32 + oct * 8;
#pragma unroll
    for (int e = 0; e < 8; ++e) {
      float x = p[e];
      unsigned short hi = f2bf(x);
      unsigned short lo = f2bf(x - bf2f(hi));
      wh[ks][e] = (short)hi;
      wl[ks][e] = (short)lo;
    }
  }

  const int aoff0 = (bg * 32 + n) * Hn + oct * 8;  // M-tile 0 A offset
  const int aoff1 = aoff0 + 16 * Hn;               // M-tile 1
  const int hsel  = (wv == 0) ? 0 : 2 * ARR;       // h arrays vs c arrays

  float c_reg[4] = {0.f, 0.f, 0.f, 0.f};  // exact fp32 c, owners tid<32 (4 j each)
  unsigned gen = 0;

  // ---- prologue: stage x_0, dt_0 ----
  if (tid < 96) {
    int bl = tid / 3, ch = tid % 3;
    float4 v = *(const float4*)(xd + ((size_t)(bg * 32 + bl) * Tn + 0) * Kn + ch * 4);
    *(float4*)(&xs_lds[bl * 12 + ch * 4]) = v;
  } else if (tid < 192) {
    int q2 = tid - 96;
    int bl = q2 / 3, ch = q2 % 3;
    float4 v = *(const float4*)(dtp + ((size_t)(bg * 32 + bl) * Tn + 0) * Kn + ch * 4);
    *(float4*)(&dt_lds[bl * 12 + ch * 4]) = v;
  }
  __syncthreads();

  for (int t = 0; t < Tn; ++t) {
    const unsigned short* sb = state + (t & 1) * SSTRIDE + hsel;

    // ---- GEMM: 2 M-tiles x 1 N-tile, K=256, split-bf16 (3 MFMA) ----
    f32x4 acc0 = {0.f, 0.f, 0.f, 0.f};
    f32x4 acc1 = {0.f, 0.f, 0.f, 0.f};
#pragma unroll
    for (int ks = 0; ks < 8; ++ks) {
      int o = ks * 32;
      bf16x8 a0h = *(const bf16x8*)(sb + aoff0 + o);
      bf16x8 a1h = *(const bf16x8*)(sb + aoff1 + o);
      bf16x8 a0l = *(const bf16x8*)(sb + ARR + aoff0 + o);
      bf16x8 a1l = *(const bf16x8*)(sb + ARR + aoff1 + o);
      acc0 = __builtin_amdgcn_mfma_f32_16x16x32_bf16(a0h, wh[ks], acc0, 0, 0, 0);
      acc1 = __builtin_amdgcn_mfma_f32_16x16x32_bf16(a1h, wh[ks], acc1, 0, 0, 0);
      acc0 = __builtin_amdgcn_mfma_f32_16x16x32_bf16(a0h, wl[ks], acc0, 0, 0, 0);
      acc1 = __builtin_amdgcn_mfma_f32_16x16x32_bf16(a1h, wl[ks], acc1, 0, 0, 0);
      acc0 = __builtin_amdgcn_mfma_f32_16x16x32_bf16(a0l, wh[ks], acc0, 0, 0, 0);
      acc1 = __builtin_amdgcn_mfma_f32_16x16x32_bf16(a1l, wh[ks], acc1, 0, 0, 0);
    }

    // ---- epilogue: D layout row=(oct*4+r) (=b_local within tile), col=n ----
    if (wv == 0) {
      int g = n & 3;
#pragma unroll
      for (int mt = 0; mt < 2; ++mt) {
        f32x4 a = mt ? acc1 : acc0;
#pragma unroll
        for (int r = 0; r < 4; ++r) {
          int bl = mt * 16 + oct * 4 + r;
          float xwv = 0.f;
#pragma unroll
          for (int kk = 0; kk < 12; ++kk) xwv += xs_lds[bl * 12 + kk] * wx[kk];
          float v = a[r] + biasv + xwv;
          float act = (g == 2) ? tanhf(v) : sigmf(v);
          g_lds[bl * 16 + n] = act;
        }
      }
    } else {
#pragma unroll
      for (int mt = 0; mt < 2; ++mt) {
        f32x4 a = mt ? acc1 : acc0;
#pragma unroll
        for (int r = 0; r < 4; ++r) {
          int bl = mt * 16 + oct * 4 + r;
          float v = a[r] + biasv;
          float cs = tanhf(v);
          float dtv = dt_lds[bl * 12 + kd];
          float coef = 1.0f / __logf(2.718281828459045f + dtv) - 1.0f;
          dsum_lds[bl * 48 + jjd * 12 + kd] = cs * coef;
        }
      }
    }
    __syncthreads();   // C: g_lds/dsum_lds ready for owner; xs(t) reads done

    ++gen;
    if (wv == 0) {
      // ---- owner update (tid<32) + packed 8B sc1 stores ----
      if (tid < 32) {
        int b = tid;
        union P { unsigned short u[4]; unsigned long long q; } ph, pl, pc, pq;
#pragma unroll
        for (int jj = 0; jj < 4; ++jj) {
          float iv = g_lds[b * 16 + jj * 4 + 0];
          float fv = g_lds[b * 16 + jj * 4 + 1];
          float gv = g_lds[b * 16 + jj * 4 + 2];
          float ov = g_lds[b * 16 + jj * 4 + 3];
          float S = 0.f;
#pragma unroll
          for (int k = 0; k < 12; ++k) S += dsum_lds[b * 48 + jj * 12 + k];
          float cst = c_reg[jj] + S;
          float cn = fv * cst + iv * gv;
          float hn = ov * tanhf(cn);
          c_reg[jj] = cn;
          ph.u[jj] = f2bf(hn);
          pl.u[jj] = f2bf(hn - bf2f(ph.u[jj]));
          pc.u[jj] = f2bf(cn);
          pq.u[jj] = f2bf(cn - bf2f(pc.u[jj]));
          if (t == Tn - 1)
            h_final[(size_t)(bg * 32 + b) * Hn + j0 + jj] = hn;
        }
        unsigned long long* db = (unsigned long long*)state
            + (size_t)((t + 1) & 1) * (SSTRIDE / 4)
            + (size_t)(bg * 32 + b) * 64 + (j0 >> 2);
        __hip_atomic_store(db + 0 * (ARR / 4), ph.q, __ATOMIC_RELAXED, __HIP_MEMORY_SCOPE_AGENT);
        __hip_atomic_store(db + 1 * (ARR / 4), pl.q, __ATOMIC_RELAXED, __HIP_MEMORY_SCOPE_AGENT);
        __hip_atomic_store(db + 2 * (ARR / 4), pc.q, __ATOMIC_RELAXED, __HIP_MEMORY_SCOPE_AGENT);
        __hip_atomic_store(db + 3 * (ARR / 4), pq.q, __ATOMIC_RELAXED, __HIP_MEMORY_SCOPE_AGENT);
      }
      // wave-0-only drain: all owner stores ack'd at MALL before slot store
      asm volatile("s_waitcnt vmcnt(0)" ::: "memory");
      if (tid == 0)
        __hip_atomic_store(gslot + (wgid & 63), gen, __ATOMIC_RELAXED,
                           __HIP_MEMORY_SCOPE_AGENT);
      // distributed poll: lane l watches slot l
      for (;;) {
        unsigned v = __hip_atomic_load(gslot + l, __ATOMIC_RELAXED,
                                       __HIP_MEMORY_SCOPE_AGENT);
        if (__all((int)(v >= gen))) break;
        __builtin_amdgcn_s_sleep(1);
      }
      if (tid == 0)
        __builtin_amdgcn_fence(__ATOMIC_ACQUIRE, "agent");  // inv vL1+L2, no wbl2
    } else if (t + 1 < Tn) {
      // ---- waves 1-3: stage x_{t+1}, dt_{t+1} during the barrier window ----
      int q = tid - 64;            // 0..191
      if (q < 96) {
        int bl = q / 3, ch = q % 3;
        float4 v = *(const float4*)(xd + ((size_t)(bg * 32 + bl) * Tn + (t + 1)) * Kn + ch * 4);
        *(float4*)(&xs_lds[bl * 12 + ch * 4]) = v;
      } else {
        int q2 = q - 96;
        int bl = q2 / 3, ch = q2 % 3;
        float4 v = *(const float4*)(dtp + ((size_t)(bg * 32 + bl) * Tn + (t + 1)) * Kn + ch * 4);
        *(float4*)(&dt_lds[bl * 12 + ch * 4]) = v;
      }
    }
    __syncthreads();   // D: barrier passed + x/dt(t+1) staged
  }
}

__global__ void out_gemv(const float* __restrict__ hf, const float* __restrict__ lw,
                         const float* __restrict__ lb, float* __restrict__ out)
{
  int b = blockIdx.x;
  int l = threadIdx.x;
  const float* row = hf + b * Hn;
  float s = row[l] * lw[l] + row[l + 64] * lw[l + 64]
          + row[l + 128] * lw[l + 128] + row[l + 192] * lw[l + 192];
#pragma unroll
  for (int off = 32; off > 0; off >>= 1) s += __shfl_down(s, off, 64);
  if (l == 0) out[b] = s + lb[0];
}

extern "C" void kernel_launch(void* const* d_in, const int* in_sizes, int n_in,
                              void* d_out, int out_size, void* d_ws, size_t ws_size,
                              hipStream_t stream)
{
  const float* xd   = (const float*)d_in[0];
  const float* dtp  = (const float*)d_in[1];
  const float* wih  = (const float*)d_in[2];
  const float* whh  = (const float*)d_in[3];
  const float* bias = (const float*)d_in[4];
  const float* wdc  = (const float*)d_in[5];
  const float* bdc  = (const float*)d_in[6];
  const float* lw   = (const float*)d_in[7];
  const float* lb   = (const float*)d_in[8];
  float* out = (float*)d_out;
  unsigned char* ws = (unsigned char*)d_ws;

  // zero slots + both state buffers (ws is poisoned 0xAA each call)
  hipMemsetAsync(ws, 0, SLOTS_BYTES + 2 * SSTRIDE * 2, stream);

  void* args[] = { (void*)&xd, (void*)&dtp, (void*)&wih, (void*)&whh,
                   (void*)&bias, (void*)&wdc, (void*)&bdc, (void*)&ws };
  hipLaunchCooperativeKernel((const void*)mtlstm_kernel, dim3(NWG), dim3(256),
                             args, 0, stream);

  const float* hf = (const float*)(ws + SLOTS_BYTES + 2 * SSTRIDE * 2);
  out_gemv<<<dim3(Bn), dim3(64), 0, stream>>>(hf, lw, lb, out);
}

// Round 10
// 4622.324 us; speedup vs baseline: 1.6733x; 1.0902x over previous
//
#include <hip/hip_runtime.h>

#define Bn   128
#define Tn   512
#define Kn   12
#define Hn   256
#define NWG  256
#define ARR      32768            // 128*256 elements per state array
#define SSTRIDE  (4*ARR)          // ushorts per state buffer (h_hi,h_lo,c_hi,c_lo)
#define CTRL_BYTES 1280           // slots[256] u32 @0, xcd_cnt[8] @1024, xcd_flag[8] @1152
#define HWREG_XCC_ID 63508        // hwreg(HW_REG_XCC_ID=20, offset 0, size 32)

typedef __attribute__((ext_vector_type(8))) short bf16x8;
typedef __attribute__((ext_vector_type(4))) float f32x4;

__device__ inline unsigned short f2bf(float x) {
  union { float f; unsigned u; } v; v.f = x;
  unsigned r = v.u + 0x7fffu + ((v.u >> 16) & 1u);
  return (unsigned short)(r >> 16);
}
__device__ inline float bf2f(unsigned short h) {
  union { unsigned u; float f; } v; v.u = ((unsigned)h) << 16;
  return v.f;
}
__device__ inline float sigmf(float x) { return 1.0f / (1.0f + __expf(-x)); }

// ROUND-9 PROVEN DATA PATH (absmax 0.0) with the barrier's cache-maintenance
// de-duplicated: rocprof model (r4->r6->r8 deltas) prices each per-WG
// buffer_inv sc1 at ~4-5us/step (32 WGs/XCD contend on one L2 tag port).
// The inv protects L2 only: stale L1 is impossible (128KB state read/step
// per CU sweeps the 32KB vL1), and L2 provably retains step t-1's clean
// state lines. So: ONE leader WG per XCD (XCC_ID + one-time rank atomic)
// polls ALL 256 slots (4/lane -> correct for ANY WG->XCD placement), does
// the single acquire fence for its XCD, publishes xcd_flag[x]=gen.
// Non-leaders poll their flag with ONE lane (r9's 64-lane x 256-WG slot
// poll was a MALL hotspot: ~16K sc1 loads/iter on 4 lines).
__global__ void __launch_bounds__(256, 1) mtlstm_kernel(
    const float* __restrict__ xd, const float* __restrict__ dtp,
    const float* __restrict__ wih, const float* __restrict__ whh,
    const float* __restrict__ bias, const float* __restrict__ wdc,
    const float* __restrict__ bdc, unsigned char* __restrict__ ws)
{
  __shared__ __align__(16) float xs_lds[32 * Kn];
  __shared__ __align__(16) float dt_lds[32 * Kn];
  __shared__ float g_lds[32 * 16];      // activated gates [b_local][jj*4+g]
  __shared__ float dsum_lds[32 * 48];   // decomp contribs [b_local][jj][k]
  __shared__ unsigned ld_info[2];       // [0]=is_leader, [1]=my xcd

  unsigned* slots    = (unsigned*)ws;                 // [256], monotone gens
  unsigned* xcd_cnt  = (unsigned*)(ws + 1024);        // [8] rank counters
  unsigned* xcd_flag = (unsigned*)(ws + 1152);        // [8] "L2 inv'd thru gen"
  unsigned short* state = (unsigned short*)(ws + CTRL_BYTES);
  float* h_final = (float*)(ws + CTRL_BYTES + 2 * SSTRIDE * 2);

  const int tid = threadIdx.x;
  const int wv  = tid >> 6;        // wave 0: gates(h); waves 1..3: decomp(c)
  const int l   = tid & 63;
  const int n   = l & 15;          // MFMA col / A-row within tile
  const int oct = l >> 4;          // k-octet

  const int wgid = blockIdx.x;
  const int bg = wgid >> 6;        // batch group 0..3 (32 b each)
  const int j0 = (wgid & 63) * 4;  // 4 j-columns per WG

  // ---- one-time: leader election (one WG per XCD) ----
  if (tid == 0) {
    unsigned xcd = __builtin_amdgcn_s_getreg(HWREG_XCC_ID) & 7u;
    unsigned r = __hip_atomic_fetch_add(xcd_cnt + xcd, 1u, __ATOMIC_RELAXED,
                                        __HIP_MEMORY_SCOPE_AGENT);
    ld_info[0] = (r == 0u);
    ld_info[1] = xcd;
  }

  // ---- one-time weight setup: per-lane 16 cols x 256 k, split hi/lo bf16 ----
  const float* rowp;
  float biasv;
  int kd = 0, jjd = 0;
  float wx[12];
  if (wv == 0) {
    int jj = n >> 2, g = n & 3;
    int grow = g * Hn + j0 + jj;
    rowp = whh + (size_t)grow * Hn;
    biasv = bias[grow];
#pragma unroll
    for (int kk = 0; kk < 12; ++kk) wx[kk] = wih[grow * 12 + kk];
  } else {
    int q = (wv - 1) * 16 + n;     // 0..47
    int jj = q / 12;
    int k  = q - jj * 12;
    kd = k; jjd = jj;
    rowp = wdc + ((size_t)k * Hn + (j0 + jj)) * Hn;
    biasv = bdc[k * Hn + j0 + jj];
#pragma unroll
    for (int kk = 0; kk < 12; ++kk) wx[kk] = 0.f;
  }

  bf16x8 wh[8], wl[8];
#pragma unroll
  for (int ks = 0; ks < 8; ++ks) {
    const float* p = rowp + ks * 32 + oct * 8;
#pragma unroll
    for (int e = 0; e < 8; ++e) {
      float x = p[e];
      unsigned short hi = f2bf(x);
      unsigned short lo = f2bf(x - bf2f(hi));
      wh[ks][e] = (short)hi;
      wl[ks][e] = (short)lo;
    }
  }

  const int aoff0 = (bg * 32 + n) * Hn + oct * 8;  // M-tile 0 A offset
  const int aoff1 = aoff0 + 16 * Hn;               // M-tile 1
  const int hsel  = (wv == 0) ? 0 : 2 * ARR;       // h arrays vs c arrays

  float c_reg[4] = {0.f, 0.f, 0.f, 0.f};  // exact fp32 c, owners tid<32 (4 j each)
  unsigned gen = 0;

  // ---- prologue: stage x_0, dt_0 ----
  if (tid < 96) {
    int bl = tid / 3, ch = tid % 3;
    float4 v = *(const float4*)(xd + ((size_t)(bg * 32 + bl) * Tn + 0) * Kn + ch * 4);
    *(float4*)(&xs_lds[bl * 12 + ch * 4]) = v;
  } else if (tid < 192) {
    int q2 = tid - 96;
    int bl = q2 / 3, ch = q2 % 3;
    float4 v = *(const float4*)(dtp + ((size_t)(bg * 32 + bl) * Tn + 0) * Kn + ch * 4);
    *(float4*)(&dt_lds[bl * 12 + ch * 4]) = v;
  }
  __syncthreads();
  const bool leader = ld_info[0] != 0u;
  const unsigned myxcd = ld_info[1];

  for (int t = 0; t < Tn; ++t) {
    const unsigned short* sb = state + (t & 1) * SSTRIDE + hsel;

    // ---- GEMM: 2 M-tiles x 1 N-tile, K=256, split-bf16 (3 MFMA) ----
    f32x4 acc0 = {0.f, 0.f, 0.f, 0.f};
    f32x4 acc1 = {0.f, 0.f, 0.f, 0.f};
#pragma unroll
    for (int ks = 0; ks < 8; ++ks) {
      int o = ks * 32;
      bf16x8 a0h = *(const bf16x8*)(sb + aoff0 + o);
      bf16x8 a1h = *(const bf16x8*)(sb + aoff1 + o);
      bf16x8 a0l = *(const bf16x8*)(sb + ARR + aoff0 + o);
      bf16x8 a1l = *(const bf16x8*)(sb + ARR + aoff1 + o);
      acc0 = __builtin_amdgcn_mfma_f32_16x16x32_bf16(a0h, wh[ks], acc0, 0, 0, 0);
      acc1 = __builtin_amdgcn_mfma_f32_16x16x32_bf16(a1h, wh[ks], acc1, 0, 0, 0);
      acc0 = __builtin_amdgcn_mfma_f32_16x16x32_bf16(a0h, wl[ks], acc0, 0, 0, 0);
      acc1 = __builtin_amdgcn_mfma_f32_16x16x32_bf16(a1h, wl[ks], acc1, 0, 0, 0);
      acc0 = __builtin_amdgcn_mfma_f32_16x16x32_bf16(a0l, wh[ks], acc0, 0, 0, 0);
      acc1 = __builtin_amdgcn_mfma_f32_16x16x32_bf16(a1l, wh[ks], acc1, 0, 0, 0);
    }

    // ---- epilogue: D layout row=(oct*4+r) (=b_local within tile), col=n ----
    if (wv == 0) {
      int g = n & 3;
#pragma unroll
      for (int mt = 0; mt < 2; ++mt) {
        f32x4 a = mt ? acc1 : acc0;
#pragma unroll
        for (int r = 0; r < 4; ++r) {
          int bl = mt * 16 + oct * 4 + r;
          float xwv = 0.f;
#pragma unroll
          for (int kk = 0; kk < 12; ++kk) xwv += xs_lds[bl * 12 + kk] * wx[kk];
          float v = a[r] + biasv + xwv;
          float act = (g == 2) ? tanhf(v) : sigmf(v);
          g_lds[bl * 16 + n] = act;
        }
      }
    } else {
#pragma unroll
      for (int mt = 0; mt < 2; ++mt) {
        f32x4 a = mt ? acc1 : acc0;
#pragma unroll
        for (int r = 0; r < 4; ++r) {
          int bl = mt * 16 + oct * 4 + r;
          float v = a[r] + biasv;
          float cs = tanhf(v);
          float dtv = dt_lds[bl * 12 + kd];
          float coef = 1.0f / __logf(2.718281828459045f + dtv) - 1.0f;
          dsum_lds[bl * 48 + jjd * 12 + kd] = cs * coef;
        }
      }
    }
    __syncthreads();   // C: g_lds/dsum_lds ready for owner; xs(t) reads done

    ++gen;
    if (wv == 0) {
      // ---- owner update (tid<32) + packed 8B sc1 stores ----
      if (tid < 32) {
        int b = tid;
        union P { unsigned short u[4]; unsigned long long q; } ph, pl, pc, pq;
#pragma unroll
        for (int jj = 0; jj < 4; ++jj) {
          float iv = g_lds[b * 16 + jj * 4 + 0];
          float fv = g_lds[b * 16 + jj * 4 + 1];
          float gv = g_lds[b * 16 + jj * 4 + 2];
          float ov = g_lds[b * 16 + jj * 4 + 3];
          float S = 0.f;
#pragma unroll
          for (int k = 0; k < 12; ++k) S += dsum_lds[b * 48 + jj * 12 + k];
          float cst = c_reg[jj] + S;
          float cn = fv * cst + iv * gv;
          float hn = ov * tanhf(cn);
          c_reg[jj] = cn;
          ph.u[jj] = f2bf(hn);
          pl.u[jj] = f2bf(hn - bf2f(ph.u[jj]));
          pc.u[jj] = f2bf(cn);
          pq.u[jj] = f2bf(cn - bf2f(pc.u[jj]));
          if (t == Tn - 1)
            h_final[(size_t)(bg * 32 + b) * Hn + j0 + jj] = hn;
        }
        unsigned long long* db = (unsigned long long*)state
            + (size_t)((t + 1) & 1) * (SSTRIDE / 4)
            + (size_t)(bg * 32 + b) * 64 + (j0 >> 2);
        __hip_atomic_store(db + 0 * (ARR / 4), ph.q, __ATOMIC_RELAXED, __HIP_MEMORY_SCOPE_AGENT);
        __hip_atomic_store(db + 1 * (ARR / 4), pl.q, __ATOMIC_RELAXED, __HIP_MEMORY_SCOPE_AGENT);
        __hip_atomic_store(db + 2 * (ARR / 4), pc.q, __ATOMIC_RELAXED, __HIP_MEMORY_SCOPE_AGENT);
        __hip_atomic_store(db + 3 * (ARR / 4), pq.q, __ATOMIC_RELAXED, __HIP_MEMORY_SCOPE_AGENT);
      }
      // wave-0-only drain: owner stores ack'd at MALL before slot store
      asm volatile("s_waitcnt vmcnt(0)" ::: "memory");
      if (tid == 0)
        __hip_atomic_store(slots + wgid, gen, __ATOMIC_RELAXED,
                           __HIP_MEMORY_SCOPE_AGENT);
      if (leader) {
        // poll ALL 256 slots (4 per lane) — placement-independent
        for (;;) {
          unsigned v0 = __hip_atomic_load(slots + l,       __ATOMIC_RELAXED, __HIP_MEMORY_SCOPE_AGENT);
          unsigned v1 = __hip_atomic_load(slots + 64 + l,  __ATOMIC_RELAXED, __HIP_MEMORY_SCOPE_AGENT);
          unsigned v2 = __hip_atomic_load(slots + 128 + l, __ATOMIC_RELAXED, __HIP_MEMORY_SCOPE_AGENT);
          unsigned v3 = __hip_atomic_load(slots + 192 + l, __ATOMIC_RELAXED, __HIP_MEMORY_SCOPE_AGENT);
          unsigned m01 = v0 < v1 ? v0 : v1;
          unsigned m23 = v2 < v3 ? v2 : v3;
          unsigned m = m01 < m23 ? m01 : m23;
          if (__all((int)(m >= gen))) break;
          __builtin_amdgcn_s_sleep(1);
        }
        __builtin_amdgcn_fence(__ATOMIC_ACQUIRE, "agent");  // ONE L2 inv per XCD
        if (tid == 0)
          __hip_atomic_store(xcd_flag + myxcd, gen, __ATOMIC_RELAXED,
                             __HIP_MEMORY_SCOPE_AGENT);
      } else {
        // single-lane flag poll: flag==gen => all state at MALL + my L2 inv'd
        for (;;) {
          unsigned v = gen;
          if (l == 0)
            v = __hip_atomic_load(xcd_flag + myxcd, __ATOMIC_RELAXED,
                                  __HIP_MEMORY_SCOPE_AGENT);
          if (__all((int)(v >= gen))) break;
          __builtin_amdgcn_s_sleep(1);
        }
      }
    } else if (t + 1 < Tn) {
      // ---- waves 1-3: stage x_{t+1}, dt_{t+1} during the barrier window ----
      int q = tid - 64;            // 0..191
      if (q < 96) {
        int bl = q / 3, ch = q % 3;
        float4 v = *(const float4*)(xd + ((size_t)(bg * 32 + bl) * Tn + (t + 1)) * Kn + ch * 4);
        *(float4*)(&xs_lds[bl * 12 + ch * 4]) = v;
      } else {
        int q2 = q - 96;
        int bl = q2 / 3, ch = q2 % 3;
        float4 v = *(const float4*)(dtp + ((size_t)(bg * 32 + bl) * Tn + (t + 1)) * Kn + ch * 4);
        *(float4*)(&dt_lds[bl * 12 + ch * 4]) = v;
      }
    }
    __syncthreads();   // D: barrier passed + x/dt(t+1) staged
  }
}

__global__ void out_gemv(const float* __restrict__ hf, const float* __restrict__ lw,
                         const float* __restrict__ lb, float* __restrict__ out)
{
  int b = blockIdx.x;
  int l = threadIdx.x;
  const float* row = hf + b * Hn;
  float s = row[l] * lw[l] + row[l + 64] * lw[l + 64]
          + row[l + 128] * lw[l + 128] + row[l + 192] * lw[l + 192];
#pragma unroll
  for (int off = 32; off > 0; off >>= 1) s += __shfl_down(s, off, 64);
  if (l == 0) out[b] = s + lb[0];
}

extern "C" void kernel_launch(void* const* d_in, const int* in_sizes, int n_in,
                              void* d_out, int out_size, void* d_ws, size_t ws_size,
                              hipStream_t stream)
{
  const float* xd   = (const float*)d_in[0];
  const float* dtp  = (const float*)d_in[1];
  const float* wih  = (const float*)d_in[2];
  const float* whh  = (const float*)d_in[3];
  const float* bias = (const float*)d_in[4];
  const float* wdc  = (const float*)d_in[5];
  const float* bdc  = (const float*)d_in[6];
  const float* lw   = (const float*)d_in[7];
  const float* lb   = (const float*)d_in[8];
  float* out = (float*)d_out;
  unsigned char* ws = (unsigned char*)d_ws;

  // zero slots + xcd counters/flags + both state buffers (ws poisoned 0xAA)
  hipMemsetAsync(ws, 0, CTRL_BYTES + 2 * SSTRIDE * 2, stream);

  void* args[] = { (void*)&xd, (void*)&dtp, (void*)&wih, (void*)&whh,
                   (void*)&bias, (void*)&wdc, (void*)&bdc, (void*)&ws };
  hipLaunchCooperativeKernel((const void*)mtlstm_kernel, dim3(NWG), dim3(256),
                             args, 0, stream);

  const float* hf = (const float*)(ws + CTRL_BYTES + 2 * SSTRIDE * 2);
  out_gemv<<<dim3(Bn), dim3(64), 0, stream>>>(hf, lw, lb, out);
}